// Round 7
// baseline (2144.964 us; speedup 1.0000x reference)
//
#include <hip/hip_runtime.h>
#include <math.h>

// Mamba2Block: B=4, S=4096, DM=768, EXPAND=2, N=128, H=4, K=4
// Processed one batch element per pass (4 passes) to cap workspace at ~117 MB.
#define B_    4
#define S_    4096
#define DM_   768
#define DI_   1536
#define MROWS 4096           // rows per pass (one batch element)
#define CHUNKS 64
#define CLEN  64

typedef unsigned short u16;
typedef unsigned int   u32;
typedef __attribute__((ext_vector_type(8))) short bf16x8;   // 8 bf16 = 4 VGPRs
typedef __attribute__((ext_vector_type(4))) float f32x4;

struct U16x4 { u16 x, y, z, w; };

// bf16 <-> f32 (RNE, bit-level)
__device__ __forceinline__ float b2f(u16 u) {
  union { u32 i; float f; } c; c.i = ((u32)u) << 16; return c.f;
}
__device__ __forceinline__ u16 f2b(float f) {
  union { float f; u32 i; } c; c.f = f;
  u32 r = c.i + 0x7fffu + ((c.i >> 16) & 1u);
  return (u16)(r >> 16);
}

// async global->LDS, 16B/lane; LDS dest = wave-uniform base + lane*16
__device__ __forceinline__ void gload16(const void* g, void* l) {
  __builtin_amdgcn_global_load_lds(
      (const __attribute__((address_space(1))) u32*)g,
      (__attribute__((address_space(3))) u32*)l, 16, 0, 0);
}

// ---------------------------------------------------------------------------
// fp32 -> (hi, lo) bf16 planes, 4 elems/thread (grids sized exactly)
// ---------------------------------------------------------------------------
__global__ __launch_bounds__(256) void split_kernel(
    const float* __restrict__ in, u16* __restrict__ hi, u16* __restrict__ lo,
    long n)
{
  long i = ((long)blockIdx.x * 256 + threadIdx.x) * 4;
  if (i >= n) return;
  float4 v = *(const float4*)(in + i);
  u16 h0 = f2b(v.x), h1 = f2b(v.y), h2 = f2b(v.z), h3 = f2b(v.w);
  U16x4 hv = {h0, h1, h2, h3};
  U16x4 lv = {f2b(v.x - b2f(h0)), f2b(v.y - b2f(h1)),
              f2b(v.z - b2f(h2)), f2b(v.w - b2f(h3))};
  *(U16x4*)(hi + i) = hv;
  *(U16x4*)(lo + i) = lv;
}

// ---------------------------------------------------------------------------
// Repack W_head (B,C thirds; 'd' third is dead code) + W_dt into combined
// 1536x1536 split-bf16 weight + fp32 bias.
//   g in [0,512)    : Bc -> W_head row h*384+128+n
//   g in [512,1024) : Cc -> W_head row h*384+256+n
//   g in [1024,1536): dt -> W_dt row g-1024
// ---------------------------------------------------------------------------
__global__ __launch_bounds__(256) void repack_kernel(
    const float* __restrict__ W_head, const float* __restrict__ b_head,
    const float* __restrict__ W_dt,   const float* __restrict__ b_dt,
    u16* __restrict__ Wch, u16* __restrict__ Wcl, float* __restrict__ bc)
{
  int bid = blockIdx.x;            // 1536*6
  int g = bid / 6;
  int e = (bid % 6) * 256 + threadIdx.x;
  const float* W; const float* bsrc; int srow;
  if (g < 512) {
    int h = g >> 7, n = g & 127;
    srow = h*384 + 128 + n; W = W_head; bsrc = b_head;
  } else if (g < 1024) {
    int g2 = g - 512; int h = g2 >> 7, n = g2 & 127;
    srow = h*384 + 256 + n; W = W_head; bsrc = b_head;
  } else {
    srow = g - 1024; W = W_dt; bsrc = b_dt;
  }
  float val = W[(long)srow*DI_ + e];
  u16 h = f2b(val);
  Wch[(long)g*DI_ + e] = h;
  Wcl[(long)g*DI_ + e] = f2b(val - b2f(h));
  if (e == 0) bc[g] = bsrc[srow];
}

// ---------------------------------------------------------------------------
// bf16x3 split MFMA GEMM: C[M,N] = (Ah+Al)[M,K] * (Bh+Bl)[N,K]^T
// 128x128 tile, BK=32, 4 waves (2x2), 64x64/wave = 4x4 16x16x32 frags.
// acc += Ah*Bh + Ah*Bl + Al*Bh (fp32 accum; dropped Al*Bl ~ 2^-16 rel).
// LDS k-block-major [4][128][8] -> frag ds_read_b128 is a free 2-way alias.
// XCD swizzle (T1): bijective (all grids %8==0).
// EPI: 0 = fp32 store; 1 = +bias, fp32 store; 2 = split hi/lo store;
//      3 = mean_h(yh)[row]*silu(acc) -> split store (yh is (H=4, S) per pass).
// ---------------------------------------------------------------------------
template<int EPI>
__global__ __launch_bounds__(256, 2) void gemm_mfma(
    const u16* __restrict__ Ah, const u16* __restrict__ Al,
    const u16* __restrict__ Bh, const u16* __restrict__ Bl,
    const float* __restrict__ bias, const float* __restrict__ yh,
    float* __restrict__ C, u16* __restrict__ Ch, u16* __restrict__ Cl,
    int M, int N, int K, int ldc)
{
  __shared__ __align__(16) u16 sAh[4][128][8], sAl[4][128][8];
  __shared__ __align__(16) u16 sBh[4][128][8], sBl[4][128][8];

  const int ntile = N >> 7;
  const int nwg = gridDim.x;
  const int wg = blockIdx.x;
  const int swz = (wg & 7) * (nwg >> 3) + (wg >> 3);   // XCD-contiguous chunks
  const int bx = swz % ntile;
  const int by = swz / ntile;
  const int m0 = by << 7, n0 = bx << 7;
  const int tid = threadIdx.x;
  const int lane = tid & 63, w = tid >> 6;
  const int wm = w >> 1, wn = w & 1;

  f32x4 acc[4][4] = {};

  const int srow_ = tid & 127;          // staging row
  const int skb0  = tid >> 7;           // staging k-block (round 0)
  const int ubase0 = (tid & ~63) * 16;  // wave-uniform LDS byte base
  const int ubase1 = ubase0 + 256 * 16;

  for (int k0 = 0; k0 < K; k0 += 32) {
    __syncthreads();                    // prior reads done before overwrite
    size_t ga = (size_t)(m0 + srow_) * K + k0 + skb0 * 8;
    size_t gb = (size_t)(n0 + srow_) * K + k0 + skb0 * 8;
    gload16(Ah + ga,      (char*)sAh + ubase0);
    gload16(Al + ga,      (char*)sAl + ubase0);
    gload16(Bh + gb,      (char*)sBh + ubase0);
    gload16(Bl + gb,      (char*)sBl + ubase0);
    gload16(Ah + ga + 16, (char*)sAh + ubase1);   // k-blocks 2,3
    gload16(Al + ga + 16, (char*)sAl + ubase1);
    gload16(Bh + gb + 16, (char*)sBh + ubase1);
    gload16(Bl + gb + 16, (char*)sBl + ubase1);
    __syncthreads();                    // compiler drains vmcnt at barrier

    const int kb = lane >> 4, rl = lane & 15;
    bf16x8 ah[4], al[4], bh[4], bl[4];
#pragma unroll
    for (int i = 0; i < 4; ++i) {
      ah[i] = *(const bf16x8*)&sAh[kb][wm*64 + i*16 + rl][0];
      al[i] = *(const bf16x8*)&sAl[kb][wm*64 + i*16 + rl][0];
      bh[i] = *(const bf16x8*)&sBh[kb][wn*64 + i*16 + rl][0];
      bl[i] = *(const bf16x8*)&sBl[kb][wn*64 + i*16 + rl][0];
    }
#pragma unroll
    for (int i = 0; i < 4; ++i)
#pragma unroll
      for (int j = 0; j < 4; ++j) {
        acc[i][j] = __builtin_amdgcn_mfma_f32_16x16x32_bf16(ah[i], bh[j], acc[i][j], 0, 0, 0);
        acc[i][j] = __builtin_amdgcn_mfma_f32_16x16x32_bf16(ah[i], bl[j], acc[i][j], 0, 0, 0);
        acc[i][j] = __builtin_amdgcn_mfma_f32_16x16x32_bf16(al[i], bh[j], acc[i][j], 0, 0, 0);
      }
  }

  // D layout: col = lane&15, row = (lane>>4)*4 + reg   [m89-verified]
  const int cl = lane & 15, rq = (lane >> 4) * 4;
  const int rowb = m0 + wm*64, colb = n0 + wn*64;
#pragma unroll
  for (int i = 0; i < 4; ++i) {
#pragma unroll
    for (int rg = 0; rg < 4; ++rg) {
      const int r = rowb + i*16 + rq + rg;
      float mult = 0.f;
      if (EPI == 3) {
        const int s = r & (S_-1);       // M==S_ per pass
        mult = 0.25f * (yh[s] + yh[S_+s] + yh[2*S_+s] + yh[3*S_+s]);
      }
#pragma unroll
      for (int j = 0; j < 4; ++j) {
        const int c = colb + j*16 + cl;
        float v = acc[i][j][rg];
        if (EPI == 1) v += bias[c];
        if (EPI == 3) v = mult * (v / (1.f + expf(-v)));
        if (EPI <= 1) {
          C[(size_t)r*ldc + c] = v;
        } else {
          u16 h = f2b(v);
          Ch[(size_t)r*ldc + c] = h;
          Cl[(size_t)r*ldc + c] = f2b(v - b2f(h));
        }
      }
    }
  }
}

// ---------------------------------------------------------------------------
// Causal depthwise conv1d K=4 (left pad 3), single batch element (S=4096)
// ---------------------------------------------------------------------------
__global__ __launch_bounds__(256) void conv_kernel(
    const u16* __restrict__ uh, const u16* __restrict__ ul,
    const float* __restrict__ w, const float* __restrict__ cb,
    u16* __restrict__ vh, u16* __restrict__ vl)
{
  int bid = blockIdx.x;            // (S/8) * (DI/256) = 512*6
  int echk = bid % 6;
  int sblk = bid / 6;              // 0..511
  int e = echk*256 + threadIdx.x;
  int s0 = sblk*8;
  float w0 = w[e*4+0], w1 = w[e*4+1], w2 = w[e*4+2], w3 = w[e*4+3];
  float bias = cb[e];
  size_t off = (size_t)s0*DI_ + e;
  float p0, p1, p2;
  if (sblk == 0) { p0 = p1 = p2 = 0.f; }
  else {
    p0 = b2f(uh[off - 3*DI_]) + b2f(ul[off - 3*DI_]);
    p1 = b2f(uh[off - 2*DI_]) + b2f(ul[off - 2*DI_]);
    p2 = b2f(uh[off - 1*DI_]) + b2f(ul[off - 1*DI_]);
  }
#pragma unroll
  for (int j = 0; j < 8; ++j) {
    float cur = b2f(uh[off + (size_t)j*DI_]) + b2f(ul[off + (size_t)j*DI_]);
    float val = fmaf(w0,p0, fmaf(w1,p1, fmaf(w2,p2, fmaf(w3,cur, bias))));
    u16 h = f2b(val);
    vh[off + (size_t)j*DI_] = h;
    vl[off + (size_t)j*DI_] = f2b(val - b2f(h));
    p0 = p1; p1 = p2; p2 = cur;
  }
}

// ---------------------------------------------------------------------------
// Chunked linear-recurrence scan over raw X rows [Bc | Cc | dt_raw] + bias.
// Single batch element. SSM transform fused into phases 1 and 3
// (bit-identical fp ops in both -> chunk recombination exact).
// ---------------------------------------------------------------------------
__global__ __launch_bounds__(128) void scan1_kernel(
    const float* __restrict__ X, const float* __restrict__ A_log,
    float* __restrict__ P, float* __restrict__ HF)
{
  int bid = blockIdx.x;            // h*64 + c  (256 blocks)
  int c = bid & 63;
  int h = bid >> 6;
  int n = threadIdx.x;             // 0..127
  float Ac = -expf(A_log[h*128 + n]);
  long base = ((long)c*CLEN)*1536 + h*128 + n;
  float hs = 0.f, Pp = 1.f;
  for (int j = 0; j < CLEN; ++j) {
    float dt = X[base + 1024];
    float Bc = X[base];
    float delta = fmaxf(dt, 0.f) + log1pf(expf(-fabsf(dt)));   // softplus
    float a = expf(delta * Ac);
    hs = fmaf(a, hs, delta * Bc);
    Pp *= a;
    base += 1536;
  }
  int idx = (h*64 + c)*128 + n;
  P[idx] = Pp; HF[idx] = hs;
}

// Phase 2: serial combine across 64 chunks. EXACTLY H*N = 512 threads.
__global__ __launch_bounds__(256) void scan2_kernel(
    const float* __restrict__ P, const float* __restrict__ HF,
    float* __restrict__ Hinit)
{
  int t = blockIdx.x*256 + threadIdx.x;   // 2 blocks -> 512 threads
  int n = t & 127;
  int h = t >> 7;                         // [0,4)
  float hi = 0.f;
  for (int c = 0; c < 64; ++c) {
    int idx = (h*64 + c)*128 + n;
    Hinit[idx] = hi;
    hi = fmaf(P[idx], hi, HF[idx]);
  }
}

// Phase 3: re-run recurrence from Hinit, emit yh[h,s] = sum_n Cc*h
__global__ __launch_bounds__(64) void scan3_kernel(
    const float* __restrict__ X, const float* __restrict__ A_log,
    const float* __restrict__ Hinit, float* __restrict__ yh)
{
  int bid = blockIdx.x;            // h*64 + c
  int c = bid & 63;
  int h = bid >> 6;
  int lane = threadIdx.x;
  float A0 = -expf(A_log[h*128 + lane]);
  float A1 = -expf(A_log[h*128 + lane + 64]);
  float h0 = Hinit[(h*64 + c)*128 + lane];
  float h1 = Hinit[(h*64 + c)*128 + lane + 64];
  long base = ((long)c*CLEN)*1536 + h*128;
  float* yo = yh + (long)h*S_ + c*CLEN;
  for (int j = 0; j < CLEN; ++j) {
    float dt0 = X[base + 1024 + lane], dt1 = X[base + 1024 + lane + 64];
    float b0  = X[base + lane],        b1  = X[base + lane + 64];
    float c0  = X[base + 512 + lane],  c1  = X[base + 512 + lane + 64];
    float d0 = fmaxf(dt0, 0.f) + log1pf(expf(-fabsf(dt0)));
    float d1 = fmaxf(dt1, 0.f) + log1pf(expf(-fabsf(dt1)));
    h0 = fmaf(expf(d0*A0), h0, d0*b0);
    h1 = fmaf(expf(d1*A1), h1, d1*b1);
    float p = fmaf(c0, h0, c1*h1);
#pragma unroll
    for (int off = 32; off; off >>= 1) p += __shfl_xor(p, off, 64);
    if (lane == 0) yo[j] = p;
    base += 1536;
  }
}

// ---------------------------------------------------------------------------
extern "C" void kernel_launch(void* const* d_in, const int* in_sizes, int n_in,
                              void* d_out, int out_size, void* d_ws, size_t ws_size,
                              hipStream_t stream)
{
  const float* x      = (const float*)d_in[0];
  const float* W_in   = (const float*)d_in[1];
  const float* conv_w = (const float*)d_in[2];
  const float* conv_b = (const float*)d_in[3];
  const float* W_head = (const float*)d_in[4];
  const float* b_head = (const float*)d_in[5];
  const float* W_dt   = (const float*)d_in[6];
  const float* b_dt   = (const float*)d_in[7];
  const float* A_log  = (const float*)d_in[8];
  const float* W_gate = (const float*)d_in[9];
  const float* W_out  = (const float*)d_in[10];
  float* out = (float*)d_out;

  char* p = (char*)d_ws;
  auto take = [&](size_t bytes) -> char* { char* r = p; p += bytes; return r; };
  // per-pass activations (one batch element, MROWS=4096)
  u16* xh  = (u16*)take((size_t)MROWS*DM_*2);
  u16* xl  = (u16*)take((size_t)MROWS*DM_*2);
  u16* uh  = (u16*)take((size_t)MROWS*DI_*2);
  u16* ul  = (u16*)take((size_t)MROWS*DI_*2);
  u16* vh  = (u16*)take((size_t)MROWS*DI_*2);   // conv out; reused as gate out
  u16* vl  = (u16*)take((size_t)MROWS*DI_*2);
  float* X = (float*)take((size_t)MROWS*1536*4);
  // weights (split once)
  u16* Wih = (u16*)take((size_t)DI_*DM_*2);
  u16* Wil = (u16*)take((size_t)DI_*DM_*2);
  u16* Wgh = (u16*)take((size_t)DI_*DI_*2);
  u16* Wgl = (u16*)take((size_t)DI_*DI_*2);
  u16* Woh = (u16*)take((size_t)DM_*DI_*2);
  u16* Wol = (u16*)take((size_t)DM_*DI_*2);
  u16* Wch = (u16*)take((size_t)1536*1536*2);
  u16* Wcl = (u16*)take((size_t)1536*1536*2);
  float* bc  = (float*)take(1536*4);
  // scan state (per pass)
  float* P   = (float*)take(32768*4);
  float* HF  = (float*)take(32768*4);
  float* Hin = (float*)take(32768*4);
  float* yh  = (float*)take((size_t)4*S_*4);   // (4,4096) fp32

  // weight splits (once)
  split_kernel<<<1152,  256, 0, stream>>>(W_in,   Wih, Wil, (long)DI_*DM_);
  split_kernel<<<2304,  256, 0, stream>>>(W_gate, Wgh, Wgl, (long)DI_*DI_);
  split_kernel<<<1152,  256, 0, stream>>>(W_out,  Woh, Wol, (long)DM_*DI_);
  repack_kernel<<<1536*6, 256, 0, stream>>>(W_head, b_head, W_dt, b_dt, Wch, Wcl, bc);

  for (int b = 0; b < B_; ++b) {
    const float* xb = x   + (size_t)b*S_*DM_;
    float* outb     = out + (size_t)b*S_*DM_;
    // 0) split x quarter
    split_kernel<<<3072, 256, 0, stream>>>(xb, xh, xl, (long)MROWS*DM_);
    // 1) u = x @ W_in^T -> split uh/ul            [4096x768 -> 1536]
    gemm_mfma<2><<<32*12, 256, 0, stream>>>(xh, xl, Wih, Wil, nullptr, nullptr,
                                            nullptr, uh, ul, MROWS, DI_, DM_, DI_);
    // 2) v = causal depthwise conv(u) + conv_b -> vh/vl
    conv_kernel<<<512*6, 256, 0, stream>>>(uh, ul, conv_w, conv_b, vh, vl);
    // 3) X = v @ Wc^T + bc (fp32 raw ssm feats)   [4096x1536 -> 1536]
    gemm_mfma<1><<<32*12, 256, 0, stream>>>(vh, vl, Wch, Wcl, bc, nullptr,
                                            X, nullptr, nullptr, MROWS, 1536, DI_, 1536);
    // 4) chunked scan (transform fused) -> yh (4,4096)
    scan1_kernel<<<256, 128, 0, stream>>>(X, A_log, P, HF);
    scan2_kernel<<<2,   256, 0, stream>>>(P, HF, Hin);
    scan3_kernel<<<256, 64,  0, stream>>>(X, A_log, Hin, yh);
    // 5) g = mean_h(yh) * silu(u @ W_gate^T) -> split (reuse vh/vl)
    gemm_mfma<3><<<32*12, 256, 0, stream>>>(uh, ul, Wgh, Wgl, nullptr, yh,
                                            nullptr, vh, vl, MROWS, DI_, DI_, DI_);
    // 6) out = g @ W_out^T                        [4096x1536 -> 768]
    gemm_mfma<0><<<32*6, 256, 0, stream>>>(vh, vl, Woh, Wol, nullptr, nullptr,
                                           outb, nullptr, nullptr, MROWS, DM_, DI_, DM_);
  }
}